// Round 1
// baseline (139.609 us; speedup 1.0000x reference)
//
#include <hip/hip_runtime.h>

#define N_NODES 4096
#define H 64
#define T_DIM 6
#define G_DIM 16

// workspace layout (float offsets)
constexpr int OFF_W2   = 0;                       // W_comb transposed [i][r] : 64*192
constexpr int OFF_OFFS = 12288;                   // 17 ints (graph offsets), reserve 32
constexpr int OFF_QS   = 12320;                   // silu(q)*scale_q : N*64
constexpr int OFF_KS   = OFF_QS + N_NODES * H;    // silu(k) : N*64
constexpr int OFF_VS   = OFF_KS + N_NODES * H;    // v : N*64
constexpr int OFF_COS  = OFF_VS + N_NODES * H;    // cos(phase) : N*8 (T=6 padded)
constexpr int OFF_SIN  = OFF_COS + N_NODES * 8;   // sin(phase) : N*8
constexpr int OFF_KVG  = OFF_SIN + N_NODES * 8;   // kv_graph : G*T*64*64
constexpr int OFF_UPD  = OFF_KVG + G_DIM * T_DIM * H * H; // update : N*64

typedef __bf16 bf16x8 __attribute__((ext_vector_type(8)));
typedef float f32x4 __attribute__((ext_vector_type(4)));

// ---------------- K0: combined weight + segment offsets ----------------
__global__ __launch_bounds__(256) void k_prep(const float* __restrict__ Wro,
                                              const float* __restrict__ Wqkv,
                                              const int* __restrict__ batch,
                                              float* __restrict__ ws) {
    int bid = blockIdx.x;
    if (bid < 48) {
        int o = bid * 256 + threadIdx.x;   // 0..12287
        int i = o / 192, r = o % 192;
        float acc = 0.f;
        #pragma unroll 8
        for (int h = 0; h < 64; ++h) acc += Wqkv[r * 64 + h] * Wro[h * 64 + i];
        ws[OFF_W2 + i * 192 + r] = acc;    // [i][r], coalesced in r
    } else {
        int g = threadIdx.x;
        if (g <= 16) {
            int lo = 0, hi = N_NODES;
            while (lo < hi) { int mid = (lo + hi) >> 1; if (batch[mid] < g) lo = mid + 1; else hi = mid; }
            ((int*)(ws + OFF_OFFS))[g] = lo;
        }
    }
}

// ---------------- K1: QKV + silu + rope phase ----------------
__global__ __launch_bounds__(256) void k_qkv(const float* __restrict__ feat,
                                             const float* __restrict__ pos,
                                             const float* __restrict__ kvecs,
                                             const int* __restrict__ batch,
                                             float* __restrict__ ws) {
    __shared__ float Wl[12288];       // [i][r] : 192-stride rows
    __shared__ float fl[16 * 64];
    int tid = threadIdx.x, blk = blockIdx.x;
    #pragma unroll
    for (int k = 0; k < 48; ++k) Wl[k * 256 + tid] = ws[OFF_W2 + k * 256 + tid];
    #pragma unroll
    for (int k = 0; k < 4; ++k) fl[k * 256 + tid] = feat[blk * 1024 + k * 256 + tid];
    __syncthreads();
    int w = tid >> 6, j = tid & 63;
    for (int mi = 0; mi < 4; ++mi) {
        int ml = w * 4 + mi;
        int n = blk * 16 + ml;
        float q = 0.f, kk = 0.f, v = 0.f;
        #pragma unroll 4
        for (int i = 0; i < 64; ++i) {
            float f = fl[ml * 64 + i];
            const float* wr = &Wl[i * 192];
            q += f * wr[j]; kk += f * wr[64 + j]; v += f * wr[128 + j];
        }
        float qs = q / (1.f + __expf(-q)) * 0.125f;  // silu * scale_q (rope is linear)
        float ks = kk / (1.f + __expf(-kk));
        ws[OFF_QS + n * 64 + j] = qs;
        ws[OFF_KS + n * 64 + j] = ks;
        ws[OFF_VS + n * 64 + j] = v;
        if (j < 6) {
            int g = batch[n];
            const float* kv = &kvecs[(g * 6 + j) * 3];
            float ph = pos[n * 3 + 0] * kv[0] + pos[n * 3 + 1] * kv[1] + pos[n * 3 + 2] * kv[2];
            ws[OFF_COS + n * 8 + j] = cosf(ph);
            ws[OFF_SIN + n * 8 + j] = sinf(ph);
        }
    }
}

// ---------------- K2: kv_graph = segment-sum of k_rope ⊗ v ----------------
__global__ __launch_bounds__(256) void k_kvg(float* __restrict__ ws) {
    __shared__ float kr8[8][64];
    __shared__ float v8[8][64];
    int bid = blockIdx.x;                  // G*T*8 = 768
    int g = bid / 48, rem = bid % 48, t = rem >> 3, ch = rem & 7;
    const int* off = (const int*)(ws + OFF_OFFS);
    int n0 = off[g] + ch * 64;
    int n1 = min(off[g + 1], n0 + 64);
    if (n0 >= n1) return;                  // uniform over block
    int tid = threadIdx.x;
    int e = tid & 63, dg = tid >> 6;
    float acc[16];
    #pragma unroll
    for (int k = 0; k < 16; ++k) acc[k] = 0.f;
    for (int base = n0; base < n1; base += 8) {
        int cnt = min(8, n1 - base);
        #pragma unroll
        for (int half = 0; half < 2; ++half) {
            int idx = half * 256 + tid;
            int ns = idx >> 6, d = idx & 63;
            float kr = 0.f, vv = 0.f;
            if (ns < cnt) {
                int n = base + ns;
                float ka = ws[OFF_KS + n * 64 + 2 * (d & 31)];
                float kb = ws[OFF_KS + n * 64 + 2 * (d & 31) + 1];
                float c = ws[OFF_COS + n * 8 + t], s = ws[OFF_SIN + n * 8 + t];
                kr = (d < 32) ? (ka * c - kb * s) : (ka * s + kb * c);
                vv = ws[OFF_VS + n * 64 + d];
            }
            kr8[ns][d] = kr; v8[ns][d] = vv;
        }
        __syncthreads();
        #pragma unroll
        for (int ns = 0; ns < 8; ++ns) {
            float vv = v8[ns][e];
            const float4* kp = (const float4*)&kr8[ns][dg * 16];
            #pragma unroll
            for (int q4 = 0; q4 < 4; ++q4) {
                float4 kq = kp[q4];
                acc[q4 * 4 + 0] += kq.x * vv; acc[q4 * 4 + 1] += kq.y * vv;
                acc[q4 * 4 + 2] += kq.z * vv; acc[q4 * 4 + 3] += kq.w * vv;
            }
        }
        __syncthreads();
    }
    float* kvg = ws + OFF_KVG + ((g * 6 + t) * 64 + dg * 16) * 64;
    #pragma unroll
    for (int k = 0; k < 16; ++k) atomicAdd(&kvg[k * 64 + e], acc[k]);
}

// ---------------- K3: update[n,e] = sum_{t,d} q_rope[t,n,d] * kvg[g,t,d,e] ----------------
__global__ __launch_bounds__(256) void k_upd(const int* __restrict__ batch, float* __restrict__ ws) {
    __shared__ float qr[4][6][64];
    int tid = threadIdx.x, blk = blockIdx.x;  // N/4 = 1024 blocks
    #pragma unroll
    for (int k = 0; k < 6; ++k) {
        int idx = k * 256 + tid;               // 0..1535
        int m = idx / 384, rem = idx % 384;
        int t = rem >> 6, d = rem & 63;
        int n = blk * 4 + m;
        float qa = ws[OFF_QS + n * 64 + 2 * (d & 31)];
        float qb = ws[OFF_QS + n * 64 + 2 * (d & 31) + 1];
        float c = ws[OFF_COS + n * 8 + t], s = ws[OFF_SIN + n * 8 + t];
        qr[m][t][d] = (d < 32) ? (qa * c - qb * s) : (qa * s + qb * c);
    }
    __syncthreads();
    int w = tid >> 6, e = tid & 63;
    int n = blk * 4 + w;
    int g = batch[n];
    const float* kvg = ws + OFF_KVG + g * (T_DIM * H * H);
    float acc = 0.f;
    #pragma unroll
    for (int t = 0; t < 6; ++t) {
        #pragma unroll 8
        for (int d = 0; d < 64; ++d)
            acc += qr[w][t][d] * kvg[(t * 64 + d) * 64 + e];
    }
    ws[OFF_UPD + n * 64 + e] = acc;
}

// ---------------- K4: node_nl via bf16 MFMA GEMM, A built on the fly ----------------
__device__ __forceinline__ bf16x8 make_afrag(const float* p, float s) {
    float4 u0 = *(const float4*)p;
    float4 u1 = *(const float4*)(p + 4);
    bf16x8 r;
    r[0] = (__bf16)(s * u0.x); r[1] = (__bf16)(s * u0.y); r[2] = (__bf16)(s * u0.z); r[3] = (__bf16)(s * u0.w);
    r[4] = (__bf16)(s * u1.x); r[5] = (__bf16)(s * u1.y); r[6] = (__bf16)(s * u1.z); r[7] = (__bf16)(s * u1.w);
    return r;
}
__device__ __forceinline__ bf16x8 make_bfrag(const float* p) {
    float4 u0 = *(const float4*)p;
    float4 u1 = *(const float4*)(p + 4);
    bf16x8 r;
    r[0] = (__bf16)u0.x; r[1] = (__bf16)u0.y; r[2] = (__bf16)u0.z; r[3] = (__bf16)u0.w;
    r[4] = (__bf16)u1.x; r[5] = (__bf16)u1.y; r[6] = (__bf16)u1.z; r[7] = (__bf16)u1.w;
    return r;
}

__global__ __launch_bounds__(256) void k_out(const float* __restrict__ sr,
                                             const float* __restrict__ Wtp,
                                             const float* __restrict__ ws,
                                             float* __restrict__ out) {
    __shared__ float sr_l[64][65];
    __shared__ float up_l[64][68];
    __shared__ float w_l[64][68];
    int tid = threadIdx.x;
    int mb = blockIdx.x & 63, kspl = blockIdx.x >> 6;   // 64 m-blocks x 8 k-splits
    int m0 = mb * 64;
    #pragma unroll
    for (int k = 0; k < 16; ++k) {
        int idx = k * 256 + tid;      // 0..4095
        int m = idx >> 6, c = idx & 63;
        sr_l[m][c] = sr[(m0 + m) * 64 + c];
        up_l[m][c] = ws[OFF_UPD + (m0 + m) * 64 + c];
    }
    __syncthreads();
    int w = tid >> 6, lane = tid & 63;
    int wm = w >> 1, wn = w & 1;
    int lr = lane & 15, lg = lane >> 4;
    f32x4 acc[2][2];
    #pragma unroll
    for (int a = 0; a < 2; ++a)
        #pragma unroll
        for (int b = 0; b < 2; ++b) acc[a][b] = (f32x4){0.f, 0.f, 0.f, 0.f};

    for (int ii = 0; ii < 8; ++ii) {
        int i = kspl * 8 + ii;
        // stage W_tp[:, i, :] -> w_l[col][j]
        #pragma unroll
        for (int k = 0; k < 4; ++k) {
            int idx = k * 256 + tid;                    // 0..1023
            int col = idx >> 4, j4 = (idx & 15) * 4;
            float4 wv = *(const float4*)&Wtp[(col * 64 + i) * 64 + j4];
            *(float4*)&w_l[col][j4] = wv;
        }
        __syncthreads();
        float s0 = sr_l[wm * 32 + lr][i];
        float s1 = sr_l[wm * 32 + 16 + lr][i];
        #pragma unroll
        for (int kc = 0; kc < 2; ++kc) {
            int j0 = kc * 32 + lg * 8;
            bf16x8 a0 = make_afrag(&up_l[wm * 32 + lr][j0], s0);
            bf16x8 a1 = make_afrag(&up_l[wm * 32 + 16 + lr][j0], s1);
            bf16x8 b0 = make_bfrag(&w_l[wn * 32 + lr][j0]);
            bf16x8 b1 = make_bfrag(&w_l[wn * 32 + 16 + lr][j0]);
            acc[0][0] = __builtin_amdgcn_mfma_f32_16x16x32_bf16(a0, b0, acc[0][0], 0, 0, 0);
            acc[0][1] = __builtin_amdgcn_mfma_f32_16x16x32_bf16(a0, b1, acc[0][1], 0, 0, 0);
            acc[1][0] = __builtin_amdgcn_mfma_f32_16x16x32_bf16(a1, b0, acc[1][0], 0, 0, 0);
            acc[1][1] = __builtin_amdgcn_mfma_f32_16x16x32_bf16(a1, b1, acc[1][1], 0, 0, 0);
        }
        __syncthreads();
    }
    #pragma unroll
    for (int mt = 0; mt < 2; ++mt)
        #pragma unroll
        for (int nt = 0; nt < 2; ++nt) {
            int row = m0 + wm * 32 + mt * 16 + lg * 4;
            int col = wn * 32 + nt * 16 + lr;
            #pragma unroll
            for (int r = 0; r < 4; ++r)
                atomicAdd(&out[(row + r) * 64 + col], acc[mt][nt][r]);
        }
}

extern "C" void kernel_launch(void* const* d_in, const int* in_sizes, int n_in,
                              void* d_out, int out_size, void* d_ws, size_t ws_size,
                              hipStream_t stream) {
    const float* node_feat    = (const float*)d_in[0];
    const float* node_feat_sr = (const float*)d_in[1];
    const float* positions    = (const float*)d_in[2];
    const float* kvecs        = (const float*)d_in[3];
    const int*   batch        = (const int*)d_in[4];
    const float* W_readout    = (const float*)d_in[5];
    const float* W_qkv        = (const float*)d_in[6];
    const float* W_tp         = (const float*)d_in[7];
    float* out = (float*)d_out;
    float* ws  = (float*)d_ws;

    hipMemsetAsync(ws + OFF_KVG, 0, G_DIM * T_DIM * H * H * sizeof(float), stream);
    hipMemsetAsync(out, 0, N_NODES * H * sizeof(float), stream);

    k_prep<<<49, 256, 0, stream>>>(W_readout, W_qkv, batch, ws);
    k_qkv<<<256, 256, 0, stream>>>(node_feat, positions, kvecs, batch, ws);
    k_kvg<<<768, 256, 0, stream>>>(ws);
    k_upd<<<1024, 256, 0, stream>>>(batch, ws);
    k_out<<<512, 256, 0, stream>>>(node_feat_sr, W_tp, ws, out);
}

// Round 2
// 126.150 us; speedup vs baseline: 1.1067x; 1.1067x over previous
//
#include <hip/hip_runtime.h>

#define NN 4096
#define HH 64
#define TT 6
#define GG 16

// workspace layout (float offsets)
constexpr int OFF_OFFS = 0;                        // 17 ints, pad to 32
constexpr int OFF_QS   = 32;                       // silu(q)*scale_q : N*64
constexpr int OFF_KS   = OFF_QS + NN * HH;         // silu(k) : N*64
constexpr int OFF_VS   = OFF_KS + NN * HH;         // v : N*64
constexpr int OFF_COS  = OFF_VS + NN * HH;         // cos(phase) : N*8 (T=6 padded)
constexpr int OFF_SIN  = OFF_COS + NN * 8;         // sin(phase) : N*8
constexpr int OFF_KVG  = OFF_SIN + NN * 8;         // kv_graph : G*T*64*64
constexpr int OFF_UPD  = OFF_KVG + GG * TT * HH * HH; // update : N*64

typedef __bf16 bf16x8 __attribute__((ext_vector_type(8)));
typedef float f32x4 __attribute__((ext_vector_type(4)));

// ---------------- K1: QKV (two-phase, in-register) + silu + rope trig
//                  + segment offsets (block 256) + zero kvg ----------------
__global__ __launch_bounds__(256) void k_qkv(const float* __restrict__ feat,
                                             const float* __restrict__ pos,
                                             const float* __restrict__ kvecs,
                                             const int* __restrict__ batch,
                                             const float* __restrict__ Wro,
                                             const float* __restrict__ Wqkv,
                                             float* __restrict__ ws) {
    int tid = threadIdx.x, blk = blockIdx.x;
    if (blk == 256) {                      // segment offsets via binary search
        int g = tid;
        if (g <= GG) {
            int lo = 0, hi = NN;
            while (lo < hi) { int mid = (lo + hi) >> 1; if (batch[mid] < g) lo = mid + 1; else hi = mid; }
            ((int*)(ws + OFF_OFFS))[g] = lo;
        }
        return;
    }
    // zero this block's kvg slice: 1536 floats = 384 float4
    {
        float4 z = {0.f, 0.f, 0.f, 0.f};
        float4* kz = (float4*)(ws + OFF_KVG) + blk * 384;
        kz[tid] = z;
        if (tid < 128) kz[256 + tid] = z;
    }
    __shared__ float Wro_l[64][66];
    __shared__ float Wq_l[192][66];
    #pragma unroll
    for (int k = 0; k < 16; ++k) {
        int idx = k * 256 + tid;
        Wro_l[idx >> 6][idx & 63] = Wro[idx];
    }
    #pragma unroll
    for (int k = 0; k < 48; ++k) {
        int idx = k * 256 + tid;
        Wq_l[idx >> 6][idx & 63] = Wqkv[idx];
    }
    __syncthreads();
    int w = tid >> 6, j = tid & 63;
    // per-lane feat: fl[mi] = feat[n_mi][j]
    float fl[4];
    #pragma unroll
    for (int mi = 0; mi < 4; ++mi) fl[mi] = feat[(blk * 16 + w * 4 + mi) * 64 + j];
    // phase 1: scal[mi] = scalars[n_mi][j] = sum_i feat[n_mi][i] * Wro[j][i]
    float scal[4] = {0.f, 0.f, 0.f, 0.f};
    #pragma unroll
    for (int i4 = 0; i4 < 16; ++i4) {
        float4 w4 = *(const float4*)&Wro_l[j][i4 * 4];
        #pragma unroll
        for (int mi = 0; mi < 4; ++mi) {
            scal[mi] += __shfl(fl[mi], i4 * 4 + 0, 64) * w4.x
                      + __shfl(fl[mi], i4 * 4 + 1, 64) * w4.y
                      + __shfl(fl[mi], i4 * 4 + 2, 64) * w4.z
                      + __shfl(fl[mi], i4 * 4 + 3, 64) * w4.w;
        }
    }
    // phase 2: q/k/v[n_mi][j] = sum_i scal[n_mi][i] * Wqkv[{j,64+j,128+j}][i]
    float qa[4] = {0.f,0.f,0.f,0.f}, ka[4] = {0.f,0.f,0.f,0.f}, va[4] = {0.f,0.f,0.f,0.f};
    #pragma unroll
    for (int i4 = 0; i4 < 16; ++i4) {
        float4 wq = *(const float4*)&Wq_l[j][i4 * 4];
        float4 wk = *(const float4*)&Wq_l[64 + j][i4 * 4];
        float4 wv = *(const float4*)&Wq_l[128 + j][i4 * 4];
        #pragma unroll
        for (int mi = 0; mi < 4; ++mi) {
            float s0 = __shfl(scal[mi], i4 * 4 + 0, 64);
            float s1 = __shfl(scal[mi], i4 * 4 + 1, 64);
            float s2 = __shfl(scal[mi], i4 * 4 + 2, 64);
            float s3 = __shfl(scal[mi], i4 * 4 + 3, 64);
            qa[mi] += s0 * wq.x + s1 * wq.y + s2 * wq.z + s3 * wq.w;
            ka[mi] += s0 * wk.x + s1 * wk.y + s2 * wk.z + s3 * wk.w;
            va[mi] += s0 * wv.x + s1 * wv.y + s2 * wv.z + s3 * wv.w;
        }
    }
    #pragma unroll
    for (int mi = 0; mi < 4; ++mi) {
        int n = blk * 16 + w * 4 + mi;
        float q = qa[mi], kk2 = ka[mi], v = va[mi];
        float qs = q / (1.f + __expf(-q)) * 0.125f;   // silu * scale_q (rope is linear)
        float ks = kk2 / (1.f + __expf(-kk2));
        ws[OFF_QS + n * 64 + j] = qs;
        ws[OFF_KS + n * 64 + j] = ks;
        ws[OFF_VS + n * 64 + j] = v;
        if (j < 6) {
            int g = batch[n];
            const float* kv = &kvecs[(g * 6 + j) * 3];
            float ph = pos[n * 3 + 0] * kv[0] + pos[n * 3 + 1] * kv[1] + pos[n * 3 + 2] * kv[2];
            ws[OFF_COS + n * 8 + j] = cosf(ph);
            ws[OFF_SIN + n * 8 + j] = sinf(ph);
        }
    }
}

// ---------------- K2: kv_graph = segment-sum of k_rope ⊗ v ----------------
__global__ __launch_bounds__(256) void k_kvg(float* __restrict__ ws) {
    __shared__ float kr8[8][64];
    __shared__ float v8[8][64];
    int bid = blockIdx.x;                  // G*T*8 = 768
    int g = bid / 48, rem = bid % 48, t = rem >> 3, ch = rem & 7;
    const int* off = (const int*)(ws + OFF_OFFS);
    int n0 = off[g] + ch * 64;
    int n1 = min(off[g + 1], n0 + 64);
    if (n0 >= n1) return;                  // uniform over block
    int tid = threadIdx.x;
    int e = tid & 63, dg = tid >> 6;
    float acc[16];
    #pragma unroll
    for (int k = 0; k < 16; ++k) acc[k] = 0.f;
    for (int base = n0; base < n1; base += 8) {
        int cnt = min(8, n1 - base);
        #pragma unroll
        for (int half = 0; half < 2; ++half) {
            int idx = half * 256 + tid;
            int ns = idx >> 6, d = idx & 63;
            float kr = 0.f, vv = 0.f;
            if (ns < cnt) {
                int n = base + ns;
                float ka2 = ws[OFF_KS + n * 64 + 2 * (d & 31)];
                float kb = ws[OFF_KS + n * 64 + 2 * (d & 31) + 1];
                float c = ws[OFF_COS + n * 8 + t], s = ws[OFF_SIN + n * 8 + t];
                kr = (d < 32) ? (ka2 * c - kb * s) : (ka2 * s + kb * c);
                vv = ws[OFF_VS + n * 64 + d];
            }
            kr8[ns][d] = kr; v8[ns][d] = vv;
        }
        __syncthreads();
        #pragma unroll
        for (int ns = 0; ns < 8; ++ns) {
            float vv = v8[ns][e];
            const float4* kp = (const float4*)&kr8[ns][dg * 16];
            #pragma unroll
            for (int q4 = 0; q4 < 4; ++q4) {
                float4 kq = kp[q4];
                acc[q4 * 4 + 0] += kq.x * vv; acc[q4 * 4 + 1] += kq.y * vv;
                acc[q4 * 4 + 2] += kq.z * vv; acc[q4 * 4 + 3] += kq.w * vv;
            }
        }
        __syncthreads();
    }
    float* kvg = ws + OFF_KVG + ((g * 6 + t) * 64 + dg * 16) * 64;
    #pragma unroll
    for (int k = 0; k < 16; ++k) atomicAdd(&kvg[k * 64 + e], acc[k]);
}

// ---------------- K3: update via MFMA: qr(32x384 bf16) @ kvg_g(384x64 bf16)
//                  + zero `out` ----------------
__global__ __launch_bounds__(256) void k_upd(float* __restrict__ ws, float* __restrict__ out) {
    int tid = threadIdx.x, bid = blockIdx.x;       // 256 blocks = 16 g x 16 chunks
    // zero out slice (must be before any early return)
    ((float4*)out)[bid * 256 + tid] = (float4){0.f, 0.f, 0.f, 0.f};
    int g = bid >> 4, ch = bid & 15;
    const int* off = (const int*)(ws + OFF_OFFS);
    int n0 = off[g] + ch * 32;
    int nend = off[g + 1];
    if (n0 >= nend) return;
    int w = tid >> 6, lane = tid & 63;
    int wm = w & 1, wn = w >> 1;
    int lr = lane & 15, lg = lane >> 4;
    int nrow = n0 + wm * 16 + lr;                  // a-frag source row
    int nc = min(nrow, nend - 1);                  // clamp for loads
    // preload qs[nc][2*lg*8 .. +15] and cos/sin rows
    float qv[16];
    const float* qsr = ws + OFF_QS + nc * 64 + lg * 16;
    #pragma unroll
    for (int u = 0; u < 4; ++u) *(float4*)&qv[u * 4] = *(const float4*)&qsr[u * 4];
    float cs[8], sn[8];
    *(float4*)&cs[0] = *(const float4*)(ws + OFF_COS + nc * 8);
    *(float4*)&cs[4] = *(const float4*)(ws + OFF_COS + nc * 8 + 4);
    *(float4*)&sn[0] = *(const float4*)(ws + OFF_SIN + nc * 8);
    *(float4*)&sn[4] = *(const float4*)(ws + OFF_SIN + nc * 8 + 4);
    const float* kvg = ws + OFF_KVG + g * (TT * HH * HH);
    int col0 = wn * 32 + lr, col1 = col0 + 16;
    f32x4 acc0 = {0.f,0.f,0.f,0.f}, acc1 = {0.f,0.f,0.f,0.f};
    #pragma unroll
    for (int kk = 0; kk < 12; ++kk) {
        int t = kk >> 1;
        float c = cs[t], s = sn[t];
        bf16x8 afr;
        #pragma unroll
        for (int ii = 0; ii < 8; ++ii) {
            float a = qv[2 * ii], b = qv[2 * ii + 1];
            float r = ((kk & 1) == 0) ? (a * c - b * s) : (a * s + b * c);
            afr[ii] = (__bf16)r;
        }
        const float* bp = kvg + (kk * 32 + lg * 8) * 64;
        bf16x8 b0, b1;
        #pragma unroll
        for (int i = 0; i < 8; ++i) {
            b0[i] = (__bf16)bp[i * 64 + col0];
            b1[i] = (__bf16)bp[i * 64 + col1];
        }
        acc0 = __builtin_amdgcn_mfma_f32_16x16x32_bf16(afr, b0, acc0, 0, 0, 0);
        acc1 = __builtin_amdgcn_mfma_f32_16x16x32_bf16(afr, b1, acc1, 0, 0, 0);
    }
    #pragma unroll
    for (int r = 0; r < 4; ++r) {
        int n = n0 + wm * 16 + lg * 4 + r;
        if (n < nend) {
            ws[OFF_UPD + n * 64 + col0] = acc0[r];
            ws[OFF_UPD + n * 64 + col1] = acc1[r];
        }
    }
}

// ---------------- K4: node_nl via bf16 MFMA GEMM, A built on the fly ----------------
__device__ __forceinline__ bf16x8 make_afrag(const float* p, float s) {
    float4 u0 = *(const float4*)p;
    float4 u1 = *(const float4*)(p + 4);
    bf16x8 r;
    r[0] = (__bf16)(s * u0.x); r[1] = (__bf16)(s * u0.y); r[2] = (__bf16)(s * u0.z); r[3] = (__bf16)(s * u0.w);
    r[4] = (__bf16)(s * u1.x); r[5] = (__bf16)(s * u1.y); r[6] = (__bf16)(s * u1.z); r[7] = (__bf16)(s * u1.w);
    return r;
}
__device__ __forceinline__ bf16x8 make_bfrag(const float* p) {
    float4 u0 = *(const float4*)p;
    float4 u1 = *(const float4*)(p + 4);
    bf16x8 r;
    r[0] = (__bf16)u0.x; r[1] = (__bf16)u0.y; r[2] = (__bf16)u0.z; r[3] = (__bf16)u0.w;
    r[4] = (__bf16)u1.x; r[5] = (__bf16)u1.y; r[6] = (__bf16)u1.z; r[7] = (__bf16)u1.w;
    return r;
}

__global__ __launch_bounds__(256) void k_out(const float* __restrict__ sr,
                                             const float* __restrict__ Wtp,
                                             const float* __restrict__ ws,
                                             float* __restrict__ out) {
    __shared__ float sr_l[64][65];
    __shared__ float up_l[64][68];
    __shared__ float w_l[64][68];
    int tid = threadIdx.x;
    int mb = blockIdx.x & 63, kspl = blockIdx.x >> 6;   // 64 m-blocks x 8 k-splits
    int m0 = mb * 64;
    #pragma unroll
    for (int k = 0; k < 16; ++k) {
        int idx = k * 256 + tid;      // 0..4095
        int m = idx >> 6, c = idx & 63;
        sr_l[m][c] = sr[(m0 + m) * 64 + c];
        up_l[m][c] = ws[OFF_UPD + (m0 + m) * 64 + c];
    }
    __syncthreads();
    int w = tid >> 6, lane = tid & 63;
    int wm = w >> 1, wn = w & 1;
    int lr = lane & 15, lg = lane >> 4;
    f32x4 acc[2][2];
    #pragma unroll
    for (int a = 0; a < 2; ++a)
        #pragma unroll
        for (int b = 0; b < 2; ++b) acc[a][b] = (f32x4){0.f, 0.f, 0.f, 0.f};

    for (int ii = 0; ii < 8; ++ii) {
        int i = kspl * 8 + ii;
        // stage W_tp[:, i, :] -> w_l[col][j]
        #pragma unroll
        for (int k = 0; k < 4; ++k) {
            int idx = k * 256 + tid;                    // 0..1023
            int col = idx >> 4, j4 = (idx & 15) * 4;
            float4 wv = *(const float4*)&Wtp[(col * 64 + i) * 64 + j4];
            *(float4*)&w_l[col][j4] = wv;
        }
        __syncthreads();
        float s0 = sr_l[wm * 32 + lr][i];
        float s1 = sr_l[wm * 32 + 16 + lr][i];
        #pragma unroll
        for (int kc = 0; kc < 2; ++kc) {
            int j0 = kc * 32 + lg * 8;
            bf16x8 a0 = make_afrag(&up_l[wm * 32 + lr][j0], s0);
            bf16x8 a1 = make_afrag(&up_l[wm * 32 + 16 + lr][j0], s1);
            bf16x8 b0 = make_bfrag(&w_l[wn * 32 + lr][j0]);
            bf16x8 b1 = make_bfrag(&w_l[wn * 32 + 16 + lr][j0]);
            acc[0][0] = __builtin_amdgcn_mfma_f32_16x16x32_bf16(a0, b0, acc[0][0], 0, 0, 0);
            acc[0][1] = __builtin_amdgcn_mfma_f32_16x16x32_bf16(a0, b1, acc[0][1], 0, 0, 0);
            acc[1][0] = __builtin_amdgcn_mfma_f32_16x16x32_bf16(a1, b0, acc[1][0], 0, 0, 0);
            acc[1][1] = __builtin_amdgcn_mfma_f32_16x16x32_bf16(a1, b1, acc[1][1], 0, 0, 0);
        }
        __syncthreads();
    }
    #pragma unroll
    for (int mt = 0; mt < 2; ++mt)
        #pragma unroll
        for (int nt = 0; nt < 2; ++nt) {
            int row = m0 + wm * 32 + mt * 16 + lg * 4;
            int col = wn * 32 + nt * 16 + lr;
            #pragma unroll
            for (int r = 0; r < 4; ++r)
                atomicAdd(&out[(row + r) * 64 + col], acc[mt][nt][r]);
        }
}

extern "C" void kernel_launch(void* const* d_in, const int* in_sizes, int n_in,
                              void* d_out, int out_size, void* d_ws, size_t ws_size,
                              hipStream_t stream) {
    const float* node_feat    = (const float*)d_in[0];
    const float* node_feat_sr = (const float*)d_in[1];
    const float* positions    = (const float*)d_in[2];
    const float* kvecs        = (const float*)d_in[3];
    const int*   batch        = (const int*)d_in[4];
    const float* W_readout    = (const float*)d_in[5];
    const float* W_qkv        = (const float*)d_in[6];
    const float* W_tp         = (const float*)d_in[7];
    float* out = (float*)d_out;
    float* ws  = (float*)d_ws;

    k_qkv<<<257, 256, 0, stream>>>(node_feat, positions, kvecs, batch, W_readout, W_qkv, ws);
    k_kvg<<<768, 256, 0, stream>>>(ws);
    k_upd<<<256, 256, 0, stream>>>(ws, out);
    k_out<<<512, 256, 0, stream>>>(node_feat_sr, W_tp, ws, out);
}